// Round 11
// baseline (1566.124 us; speedup 1.0000x reference)
//
#include <hip/hip_runtime.h>

// ---------------------------------------------------------------------------
// Attention layer: qkv proj -> RoPE -> concat KV cache -> softmax attn -> out proj
// B=4 Sq=1024 Skv_cache=1024 H=16 D=128 D_MODEL=2048
// bf16 MFMA everywhere. GEMMs: 16x16x32 MFMA (r8 frag addressing, 0-conflict
// 2-bit swizzle), ring-2 dbuf counted-vmcnt, 48KB LDS -> 3 blocks/CU
// (24 waves/CU TLP covers the barrier stalls; r5 showed occupancy wins).
// Flash attention: r5 structure (32 q/wave, dbuf K/V), grid 512.
// ---------------------------------------------------------------------------

typedef __bf16 bf16x8 __attribute__((ext_vector_type(8)));
typedef float f32x4 __attribute__((ext_vector_type(4)));
typedef unsigned short u16x8 __attribute__((ext_vector_type(8)));
typedef unsigned short u16x4 __attribute__((ext_vector_type(4)));

__device__ __forceinline__ float b2f(unsigned short u) {
  return __builtin_bit_cast(float, (unsigned int)u << 16);
}
__device__ __forceinline__ unsigned short f2b(float f) {
  unsigned int x = __builtin_bit_cast(unsigned int, f);
  x += 0x7fffu + ((x >> 16) & 1u);   // RNE (finite values only)
  return (unsigned short)(x >> 16);
}
__device__ __forceinline__ unsigned int cvt_pk_bf16(float lo, float hi) {
  unsigned int r;
  asm("v_cvt_pk_bf16_f32 %0, %1, %2" : "=v"(r) : "v"(lo), "v"(hi));
  return r;
}
__device__ __forceinline__ void gload_lds16(const void* g, void* l) {
  __builtin_amdgcn_global_load_lds(
      (__attribute__((address_space(1))) void*)(g),
      (__attribute__((address_space(3))) void*)(l), 16, 0, 0);
}
__device__ __forceinline__ void barrier_nodrain() {
  asm volatile("" ::: "memory");
  __builtin_amdgcn_s_barrier();
  asm volatile("" ::: "memory");
}

// ---------------- trig table: cos/sin of (1024+s)*theta^(-i/64) ------------
__global__ void build_trig(float* __restrict__ cs, float* __restrict__ sn) {
  int idx = blockIdx.x * 256 + threadIdx.x;   // 65536 = 1024 s * 64 i
  int s = idx >> 6, i = idx & 63;
  float inv = exp2f(-(float)i * (13.287712379549449f / 64.0f)); // 10000^(-i/64)
  float ang = (float)(1024 + s) * inv;
  cs[idx] = cosf(ang);
  sn[idx] = sinf(ang);
}

// ---------------- f32 -> bf16 convert (8/thread) ---------------------------
__global__ void conv_bf16(const float* __restrict__ in, unsigned short* __restrict__ out) {
  size_t i = ((size_t)blockIdx.x * 256 + threadIdx.x) * 8;
  float4 a = *(const float4*)(in + i);
  float4 b = *(const float4*)(in + i + 4);
  u16x8 v;
  v[0] = f2b(a.x); v[1] = f2b(a.y); v[2] = f2b(a.z); v[3] = f2b(a.w);
  v[4] = f2b(b.x); v[5] = f2b(b.y); v[6] = f2b(b.z); v[7] = f2b(b.w);
  *(u16x8*)(out + i) = v;
}

// ---------------- transposed convert: in[R][C] f32 -> out[C][R] bf16 -------
__global__ __launch_bounds__(256) void transpose_conv(
    const float* __restrict__ in, unsigned short* __restrict__ out, int R, int C) {
  __shared__ float tile[32][33];
  int c0 = blockIdx.x * 32, r0 = blockIdx.y * 32;
  int tx = threadIdx.x & 31, ty = threadIdx.x >> 5;   // 32 x 8
#pragma unroll
  for (int j = 0; j < 4; ++j)
    tile[ty + j * 8][tx] = in[(size_t)(r0 + ty + j * 8) * C + c0 + tx];
  __syncthreads();
#pragma unroll
  for (int j = 0; j < 4; ++j)
    out[(size_t)(c0 + ty + j * 8) * R + r0 + tx] = f2b(tile[tx][ty + j * 8]);
}

// ---------------- cache_k f32 -> K_full[:, :1024] bf16 ---------------------
__global__ void copy_k(const float* __restrict__ ck, unsigned short* __restrict__ Kf) {
  size_t idx = ((size_t)blockIdx.x * 256 + threadIdx.x) * 4;  // over 64*1024*128
  size_t bh = idx >> 17, rem = idx & 131071;                  // 1024*128 = 2^17
  float4 a = *(const float4*)(ck + idx);
  u16x4 v;
  v[0] = f2b(a.x); v[1] = f2b(a.y); v[2] = f2b(a.z); v[3] = f2b(a.w);
  *(u16x4*)(Kf + bh * 262144 + rem) = v;                      // 2048*128 row block
}

// ---------------- RoPE q,k from qkv; q scaled by log2e/sqrt(128) -----------
__global__ __launch_bounds__(256) void rope_qk(
    const unsigned short* __restrict__ qkv, const float* __restrict__ cs,
    const float* __restrict__ sn, unsigned short* __restrict__ Qb,
    unsigned short* __restrict__ Kf) {
  int row = blockIdx.x;                 // b*1024 + s
  int b = row >> 10, s = row & 1023;
#pragma unroll
  for (int it = 0; it < 4; ++it) {
    int item = it * 256 + threadIdx.x;  // 16 heads * 64 pairs
    int h = item >> 6, i = item & 63;
    const unsigned short* base = qkv + (size_t)row * 6144 + h * 384;
    float q1 = b2f(base[i]),       q2 = b2f(base[64 + i]);
    float k1 = b2f(base[128 + i]), k2 = b2f(base[192 + i]);
    float c = cs[s * 64 + i], sv = sn[s * 64 + i];
    const float scale = 0.12751738f;    // log2(e)/sqrt(128): softmax in base-2
    size_t bh = (size_t)(b * 16 + h);
    unsigned short* qd = Qb + (bh * 1024 + s) * 128;
    qd[i]      = f2b((q1 * c - q2 * sv) * scale);
    qd[64 + i] = f2b((q2 * c + q1 * sv) * scale);
    unsigned short* kd = Kf + (bh * 2048 + 1024 + s) * 128;
    kd[i]      = f2b(k1 * c - k2 * sv);
    kd[64 + i] = f2b(k2 * c + k1 * sv);
  }
}

// ---------------- V^T build: V_t[b][h][d][s], s<1024 from cache, else qkv --
__global__ __launch_bounds__(256) void build_vt(
    const float* __restrict__ cv, const unsigned short* __restrict__ qkv,
    unsigned short* __restrict__ Vt) {
  __shared__ float tile[32][33];
  int bhid = blockIdx.z;
  int s0 = blockIdx.x * 32, d0 = blockIdx.y * 32;
  int tx = threadIdx.x & 31, ty = threadIdx.x >> 5;
  int b = bhid >> 4, h = bhid & 15;
#pragma unroll
  for (int j = 0; j < 4; ++j) {
    int s = s0 + ty + j * 8, d = d0 + tx;
    float v;
    if (s < 1024) v = cv[((size_t)bhid * 1024 + s) * 128 + d];
    else v = b2f(qkv[((size_t)b * 1024 + (s - 1024)) * 6144 + h * 384 + 256 + d]);
    tile[ty + j * 8][tx] = v;
  }
  __syncthreads();
#pragma unroll
  for (int j = 0; j < 4; ++j) {
    int d = d0 + ty + j * 8, s = s0 + tx;
    Vt[((size_t)bhid * 128 + d) * 2048 + s] = f2b(tile[tx][ty + j * 8]);
  }
}

// ---------------- GEMM: C[M][N] = A[M][K] * B^T  (B given as [N][K]) -------
// 16x16x32 MFMA, BM=256 BN=128 BK=32, 8 waves (4M x 2N), per-wave 64x64.
// Ring-2 double buffer, LDS 2x24KB = 48KB -> 3 blocks/CU (24 waves/CU; TLP
// covers barrier stalls -- r5 vs r6/r7 showed occupancy dominates).
// 2-bit XOR swizzle (r8, measured 0 conflicts): LDS[r][c16] = src[r][c16 ^
// ((r>>1)&3)]; frag rows step 16 -> (row>>1)&3 == (l15>>1)&3 per-lane const.
// Ledger (attn-proven 2-barrier dbuf): stage = 3 loads. Prologue stage(0).
// Iter t: barrier#1 (compute(t-1) done -> buf (t+1)&1 free); stage((t+1)&1)
// -> outstanding {t,t+1} = 6; vmcnt(3) -> tile t's 3 retired (FIFO); tail
// iter drains vmcnt(0). barrier#2 publishes tile t block-wide; compute(t).
template <int M, int N, int K, bool OUT_BF16>
__global__ __launch_bounds__(512, 6) void gemm_ring(
    const unsigned short* __restrict__ A, const unsigned short* __restrict__ B,
    void* __restrict__ Cout) {
  __shared__ __align__(16) char lds[2 * 24576];
  constexpr int NT = N / 128;
  constexpr int Kt = K / 32;
  int bid = blockIdx.x;
  int tm = bid / NT, tn = bid % NT;
  int tid = threadIdx.x;
  int lane = tid & 63, wave = tid >> 6;
  int wr = (wave >> 1) * 64, wc = (wave & 1) * 64;
  int l15 = lane & 15, g = lane >> 4;
  int rcol = (g * 16) ^ (((l15 >> 1) & 3) << 4);   // swizzled chunk in 64B row

  int p = tid * 16;   // byte position in a 16KB/8KB staging region
  int srcCol = (p & 63) ^ (((p >> 7) & 3) << 4);   // inverse swizzle on source
  const unsigned short* aSrc0 = A + (size_t)(tm * 256 + (p >> 6)) * K + (srcCol >> 1);
  const unsigned short* aSrc1 = aSrc0 + (size_t)128 * K;   // rows 128..255
  const unsigned short* bSrc  = B + (size_t)(tn * 128 + (p >> 6)) * K + (srcCol >> 1);

  f32x4 acc[4][4] = {};

  auto stage = [&](int s) {
    char* base = (char*)lds + s * 24576;
    gload_lds16(aSrc0, base + p);
    gload_lds16(aSrc1, base + 8192 + p);
    gload_lds16(bSrc,  base + 16384 + p);
    aSrc0 += 32; aSrc1 += 32; bSrc += 32;
  };

  stage(0);
  for (int t = 0; t < Kt; ++t) {
    int cur = t & 1;
    barrier_nodrain();               // compute(t-1) done -> buf cur^1 free
    if (t + 1 < Kt) {
      stage(cur ^ 1);
      asm volatile("s_waitcnt vmcnt(3)" ::: "memory");   // tile t arrived (mine)
    } else {
      asm volatile("s_waitcnt vmcnt(0)" ::: "memory");   // tail drain
    }
    barrier_nodrain();               // tile t visible block-wide
    const char* As_ = (const char*)lds + cur * 24576;
    const char* Bs_ = As_ + 16384;
    bf16x8 af[4], bfr[4];
#pragma unroll
    for (int m = 0; m < 4; ++m)
      af[m] = *(const bf16x8*)(As_ + (wr + m * 16 + l15) * 64 + rcol);
#pragma unroll
    for (int n = 0; n < 4; ++n)
      bfr[n] = *(const bf16x8*)(Bs_ + (wc + n * 16 + l15) * 64 + rcol);
    __builtin_amdgcn_s_setprio(1);
#pragma unroll
    for (int m = 0; m < 4; ++m)
#pragma unroll
      for (int n = 0; n < 4; ++n)
        acc[m][n] = __builtin_amdgcn_mfma_f32_16x16x32_bf16(af[m], bfr[n], acc[m][n], 0, 0, 0);
    __builtin_amdgcn_s_setprio(0);
  }

#pragma unroll
  for (int m = 0; m < 4; ++m) {
    int row0 = tm * 256 + wr + m * 16 + g * 4;
#pragma unroll
    for (int n = 0; n < 4; ++n) {
      int col = tn * 128 + wc + n * 16 + l15;
#pragma unroll
      for (int r = 0; r < 4; ++r) {
        size_t off = (size_t)(row0 + r) * N + col;
        if constexpr (OUT_BF16) ((unsigned short*)Cout)[off] = f2b(acc[m][n][r]);
        else ((float*)Cout)[off] = acc[m][n][r];
      }
    }
  }
}

// ---------------- Flash attention ------------------------------------------
// grid = 512: bh (64) x q-tile (8 of 128 rows). 4 waves x 32 q rows each
// (2 q-sets of 16 per wave -> each K/V A-frag LDS read feeds 2 MFMAs; the
// kernel was LDS-BW-bound at q=16). Double-buffered K/V, counted vmcnt(8).
__global__ __launch_bounds__(256, 2) void attn_kernel(
    const unsigned short* __restrict__ Qb,   // [64][1024][128], pre-scaled
    const unsigned short* __restrict__ Kf,   // [64][2048][128]
    const unsigned short* __restrict__ Vt,   // [64][128][2048]
    unsigned short* __restrict__ Out) {      // [4096][2048] = [b][s][h*128+d]
  __shared__ __align__(16) unsigned short Ks[2][64 * 128];  // 2x16KB, swizzled
  __shared__ __align__(16) unsigned short Vs[2][64 * 128];  // 2x16KB, swizzled
  __shared__ __align__(16) char PsRaw[4 * 2 * 2048];        // 16KB: wave, qset
  // total LDS = 81920 -> exactly 2 blocks/CU

  int raw = blockIdx.x;
  int sb = (raw & 7) * 64 + (raw >> 3);     // XCD swizzle: 8 heads per XCD
  int bh = sb >> 3, qt = sb & 7;
  int tid = threadIdx.x, lane = tid & 63, wave = tid >> 6;
  int l15 = lane & 15, g = lane >> 4;
  int swz = (l15 & 7) << 4;

  int qrow0 = qt * 128 + wave * 32;
  bf16x8 qf0[4], qf1[4];
  const unsigned short* qp0 = Qb + ((size_t)(bh * 1024 + qrow0 + l15)) * 128;
#pragma unroll
  for (int kk = 0; kk < 4; ++kk) {
    qf0[kk] = *(const bf16x8*)(qp0 + kk * 32 + g * 8);
    qf1[kk] = *(const bf16x8*)(qp0 + 16 * 128 + kk * 32 + g * 8);
  }

  u16x8 ou;
#pragma unroll
  for (int j = 0; j < 8; ++j) ou[j] = 0x3F80;           // bf16 1.0
  bf16x8 ones = __builtin_bit_cast(bf16x8, ou);

  // hoisted staging pointers (incremented per kv-tile)
  const unsigned short* Kbase = Kf + (size_t)bh * 2048 * 128;
  const unsigned short* Vbase = Vt + (size_t)bh * 128 * 2048;
  const unsigned short* kptr[4];
  const unsigned short* vptr[4];
  char* kdst0[4];
  char* vdst0[4];
#pragma unroll
  for (int is = 0; is < 4; ++is) {
    int p = tid * 16 + is * 4096;
    int lgk = p ^ (((p >> 8) & 7) << 4);          // K rows = 256B
    kptr[is] = Kbase + (size_t)(lgk >> 8) * 128 + ((lgk & 255) >> 1);
    kdst0[is] = (char*)Ks + is * 4096 + (tid & 192) * 16;
    int lgv = p ^ (((p >> 7) & 7) << 4);          // V^T rows = 128B
    vptr[is] = Vbase + (size_t)(lgv >> 7) * 2048 + ((lgv & 127) >> 1);
    vdst0[is] = (char*)Vs + is * 4096 + (tid & 192) * 16;
  }
  char* ps0 = PsRaw + wave * 4096 + l15 * 128;
  char* ps1 = ps0 + 2048;

  auto stage = [&](int buf) {
#pragma unroll
    for (int is = 0; is < 4; ++is) {
      gload_lds16(kptr[is], kdst0[is] + buf * 16384);  kptr[is] += 64 * 128;
      gload_lds16(vptr[is], vdst0[is] + buf * 16384);  vptr[is] += 64;
    }
  };

  float mrun0 = -1e30f, mrun1 = -1e30f;
  f32x4 acc0[8] = {}, acc1[8] = {};
  f32x4 accl0 = {}, accl1 = {};

  // softmax+pack for one q-set (all loops unrolled -> static indexing)
  auto softmax_pack = [&](f32x4* st, float& mrun, f32x4* accp, f32x4& accl,
                          char* ps) {
    float m0 = fmaxf(fmaxf(st[0][0], st[0][1]), st[0][2]);
    float m1 = fmaxf(fmaxf(st[0][3], st[1][0]), st[1][1]);
    float m2 = fmaxf(fmaxf(st[1][2], st[1][3]), st[2][0]);
    float m3 = fmaxf(fmaxf(st[2][1], st[2][2]), st[2][3]);
    float m4 = fmaxf(fmaxf(st[3][0], st[3][1]), st[3][2]);
    float pmax = fmaxf(fmaxf(fmaxf(m0, m1), fmaxf(m2, m3)), fmaxf(m4, st[3][3]));
    pmax = fmaxf(pmax, __shfl_xor(pmax, 16));
    pmax = fmaxf(pmax, __shfl_xor(pmax, 32));
    if (!__all(pmax - mrun <= 8.0f)) {          // defer-max (T13)
      float mnew = fmaxf(mrun, pmax);
      float corr = exp2f(mrun - mnew);
      accl *= corr;
#pragma unroll
      for (int mt = 0; mt < 8; ++mt) accp[mt] *= corr;
      mrun = mnew;
    }
#pragma unroll
    for (int t = 0; t < 4; ++t) {
      float p0 = exp2f(st[t][0] - mrun);
      float p1 = exp2f(st[t][1] - mrun);
      float p2 = exp2f(st[t][2] - mrun);
      float p3 = exp2f(st[t][3] - mrun);
      uint2 w;
      w.x = cvt_pk_bf16(p0, p1);
      w.y = cvt_pk_bf16(p2, p3);
      *(uint2*)(ps + ((t * 32 + g * 8) ^ swz)) = w;
    }
  };

  stage(0);
  for (int it = 0; it < 32; ++it) {
    int cur = it & 1;
    barrier_nodrain();          // prev compute done -> buf cur^1 reads retired
    if (it + 1 < 32) {
      stage(cur ^ 1);
      asm volatile("s_waitcnt vmcnt(8)" ::: "memory");  // tile it arrived (mine)
    } else {
      asm volatile("s_waitcnt vmcnt(0)" ::: "memory");  // tail drain
    }
    barrier_nodrain();          // tile it visible block-wide
    const char* ksA = (const char*)Ks + cur * 16384 + l15 * 256;
    const char* vsA = (const char*)Vs + cur * 16384 + l15 * 128;

    // S^T tiles: 4 x (16 kv x 16 q) x 2 q-sets; one A-read feeds 2 MFMAs
    f32x4 st0[4] = {}, st1[4] = {};
#pragma unroll
    for (int kk = 0; kk < 4; ++kk) {
#pragma unroll
      for (int t = 0; t < 4; ++t) {
        bf16x8 a = *(const bf16x8*)(ksA + t * 4096 + ((kk * 64 + g * 16) ^ swz));
        st0[t] = __builtin_amdgcn_mfma_f32_16x16x32_bf16(a, qf0[kk], st0[t], 0, 0, 0);
        st1[t] = __builtin_amdgcn_mfma_f32_16x16x32_bf16(a, qf1[kk], st1[t], 0, 0, 0);
      }
    }

    softmax_pack(st0, mrun0, acc0, accl0, ps0);
    softmax_pack(st1, mrun1, acc1, accl1, ps1);

    // out^T += V^T * P^T (both q-sets per V A-read); lsum via ones-MFMA
#pragma unroll
    for (int k2 = 0; k2 < 2; ++k2) {
      bf16x8 p0 = *(const bf16x8*)(ps0 + ((k2 * 64 + g * 16) ^ swz));
      bf16x8 p1 = *(const bf16x8*)(ps1 + ((k2 * 64 + g * 16) ^ swz));
      accl0 = __builtin_amdgcn_mfma_f32_16x16x32_bf16(ones, p0, accl0, 0, 0, 0);
      accl1 = __builtin_amdgcn_mfma_f32_16x16x32_bf16(ones, p1, accl1, 0, 0, 0);
#pragma unroll
      for (int mt = 0; mt < 8; ++mt) {
        bf16x8 a = *(const bf16x8*)(vsA + mt * 2048 + ((k2 * 64 + g * 16) ^ swz));
        acc0[mt] = __builtin_amdgcn_mfma_f32_16x16x32_bf16(a, p0, acc0[mt], 0, 0, 0);
        acc1[mt] = __builtin_amdgcn_mfma_f32_16x16x32_bf16(a, p1, acc1[mt], 0, 0, 0);
      }
    }
  }

  float inv0 = 1.f / accl0[0];
  float inv1 = 1.f / accl1[0];
  int b = bh >> 4, h = bh & 15;
  int sq = qt * 128 + wave * 32 + l15;
  unsigned short* orow0 = Out + ((size_t)(b * 1024 + sq) * 16 + h) * 128;
  unsigned short* orow1 = orow0 + (size_t)16 * 2048;
#pragma unroll
  for (int mt = 0; mt < 8; ++mt) {
    uint2 w0, w1;
    w0.x = cvt_pk_bf16(acc0[mt][0] * inv0, acc0[mt][1] * inv0);
    w0.y = cvt_pk_bf16(acc0[mt][2] * inv0, acc0[mt][3] * inv0);
    w1.x = cvt_pk_bf16(acc1[mt][0] * inv1, acc1[mt][1] * inv1);
    w1.y = cvt_pk_bf16(acc1[mt][2] * inv1, acc1[mt][3] * inv1);
    *(uint2*)(orow0 + mt * 16 + g * 4) = w0;
    *(uint2*)(orow1 + mt * 16 + g * 4) = w1;
  }
}

// ---------------------------------------------------------------------------
extern "C" void kernel_launch(void* const* d_in, const int* in_sizes, int n_in,
                              void* d_out, int out_size, void* d_ws, size_t ws_size,
                              hipStream_t stream) {
  const float* x       = (const float*)d_in[0];
  const float* cache_k = (const float*)d_in[1];
  const float* cache_v = (const float*)d_in[2];
  const float* w_qkv   = (const float*)d_in[3];
  const float* w_o     = (const float*)d_in[4];
  float* out = (float*)d_out;

  // workspace layout (~176.5 MiB)
  char* W = (char*)d_ws;
  constexpr size_t O_TRIG = 0;                       // 2 * 256KB
  constexpr size_t O_XB   = 524288;                  // 16MB (reused as attn_out)
  constexpr size_t O_WQT  = O_XB  + 16777216;        // 24MB
  constexpr size_t O_WOT  = O_WQT + 25165824;        // 8MB
  constexpr size_t O_QKV  = O_WOT + 8388608;         // 48MB
  constexpr size_t O_QB   = O_QKV + 50331648;        // 16MB
  constexpr size_t O_KF   = O_QB  + 16777216;        // 32MB
  constexpr size_t O_VT   = O_KF  + 33554432;        // 32MB
  float* cs_tab = (float*)(W + O_TRIG);
  float* sn_tab = (float*)(W + O_TRIG + 262144);
  unsigned short* xb   = (unsigned short*)(W + O_XB);
  unsigned short* wqT  = (unsigned short*)(W + O_WQT);
  unsigned short* woT  = (unsigned short*)(W + O_WOT);
  unsigned short* qkv  = (unsigned short*)(W + O_QKV);
  unsigned short* qb   = (unsigned short*)(W + O_QB);
  unsigned short* Kf   = (unsigned short*)(W + O_KF);
  unsigned short* Vt   = (unsigned short*)(W + O_VT);
  unsigned short* attn_out = xb;   // xb dead after gemm1

  build_trig<<<256, 256, 0, stream>>>(cs_tab, sn_tab);
  conv_bf16<<<4096, 256, 0, stream>>>(x, xb);                       // 8.4M elems
  transpose_conv<<<dim3(192, 64), 256, 0, stream>>>(w_qkv, wqT, 2048, 6144);
  transpose_conv<<<dim3(64, 64), 256, 0, stream>>>(w_o, woT, 2048, 2048);
  gemm_ring<4096, 6144, 2048, true><<<768, 512, 0, stream>>>(xb, wqT, qkv);
  rope_qk<<<4096, 256, 0, stream>>>(qkv, cs_tab, sn_tab, qb, Kf);
  copy_k<<<8192, 256, 0, stream>>>(cache_k, Kf);
  build_vt<<<dim3(64, 4, 64), 256, 0, stream>>>(cache_v, qkv, Vt);
  attn_kernel<<<512, 256, 0, stream>>>(qb, Kf, Vt, attn_out);
  gemm_ring<4096, 2048, 2048, false><<<256, 512, 0, stream>>>(attn_out, woT, out);
}

// Round 12
// 318.988 us; speedup vs baseline: 4.9097x; 4.9097x over previous
//
#include <hip/hip_runtime.h>

// ---------------------------------------------------------------------------
// Attention layer: qkv proj -> RoPE -> concat KV cache -> softmax attn -> out proj
// B=4 Sq=1024 Skv_cache=1024 H=16 D=128 D_MODEL=2048
// bf16 MFMA everywhere. GEMMs: r8-exact ring-3 counted-vmcnt (BM256 BN128
// BK32, launch_bounds(512,4) -- (512,6) caused accumulator spills, r11:
// VGPR 40, 5GB scratch traffic, 10x regression). 2-bit XOR swizzle, 0 confl.
// Aux kernels fused: prep_fused (conv+2xtranspose+copy_k+trig, 5->1 launch)
// and post_fused (rope+build_vt, 2->1). Flash attention: r5 structure.
// ---------------------------------------------------------------------------

typedef __bf16 bf16x8 __attribute__((ext_vector_type(8)));
typedef float f32x4 __attribute__((ext_vector_type(4)));
typedef unsigned short u16x8 __attribute__((ext_vector_type(8)));
typedef unsigned short u16x4 __attribute__((ext_vector_type(4)));

__device__ __forceinline__ float b2f(unsigned short u) {
  return __builtin_bit_cast(float, (unsigned int)u << 16);
}
__device__ __forceinline__ unsigned short f2b(float f) {
  unsigned int x = __builtin_bit_cast(unsigned int, f);
  x += 0x7fffu + ((x >> 16) & 1u);   // RNE (finite values only)
  return (unsigned short)(x >> 16);
}
__device__ __forceinline__ unsigned int cvt_pk_bf16(float lo, float hi) {
  unsigned int r;
  asm("v_cvt_pk_bf16_f32 %0, %1, %2" : "=v"(r) : "v"(lo), "v"(hi));
  return r;
}
__device__ __forceinline__ void gload_lds16(const void* g, void* l) {
  __builtin_amdgcn_global_load_lds(
      (__attribute__((address_space(1))) void*)(g),
      (__attribute__((address_space(3))) void*)(l), 16, 0, 0);
}
__device__ __forceinline__ void barrier_nodrain() {
  asm volatile("" ::: "memory");
  __builtin_amdgcn_s_barrier();
  asm volatile("" ::: "memory");
}

// ---------------- prep_fused: all input-only data movement in ONE launch ---
// blocks [0,4096):        conv_bf16 of x (8 elems/thread)
// blocks [4096,16384):    transpose_conv w_qkv [2048][6144] -> wqT [6144][2048]
// blocks [16384,20480):   transpose_conv w_o   [2048][2048] -> woT
// blocks [20480,28672):   copy_k cache_k f32 -> Kf[:, :1024] bf16
// blocks [28672,28928):   build_trig (cos/sin tables)
__global__ __launch_bounds__(256) void prep_fused(
    const float* __restrict__ x, const float* __restrict__ ck,
    const float* __restrict__ wqkv, const float* __restrict__ wo,
    unsigned short* __restrict__ xb, unsigned short* __restrict__ Kf,
    unsigned short* __restrict__ wqT, unsigned short* __restrict__ woT,
    float* __restrict__ cs, float* __restrict__ sn) {
  __shared__ float tile[32][33];
  int id = blockIdx.x;
  if (id < 4096) {                                   // conv_bf16
    size_t i = ((size_t)id * 256 + threadIdx.x) * 8;
    float4 a = *(const float4*)(x + i);
    float4 b = *(const float4*)(x + i + 4);
    u16x8 v;
    v[0] = f2b(a.x); v[1] = f2b(a.y); v[2] = f2b(a.z); v[3] = f2b(a.w);
    v[4] = f2b(b.x); v[5] = f2b(b.y); v[6] = f2b(b.z); v[7] = f2b(b.w);
    *(u16x8*)(xb + i) = v;
  } else if (id < 20480) {                           // two transposes
    const float* in;  unsigned short* out;  int R, C, idx;
    if (id < 16384) { in = wqkv; out = wqT; R = 2048; C = 6144; idx = id - 4096; }
    else            { in = wo;   out = woT; R = 2048; C = 2048; idx = id - 16384; }
    int nc = C >> 5;
    int c0 = (idx % nc) * 32, r0 = (idx / nc) * 32;
    int tx = threadIdx.x & 31, ty = threadIdx.x >> 5;
#pragma unroll
    for (int j = 0; j < 4; ++j)
      tile[ty + j * 8][tx] = in[(size_t)(r0 + ty + j * 8) * C + c0 + tx];
    __syncthreads();
#pragma unroll
    for (int j = 0; j < 4; ++j)
      out[(size_t)(c0 + ty + j * 8) * R + r0 + tx] = f2b(tile[tx][ty + j * 8]);
  } else if (id < 28672) {                           // copy_k
    size_t idx = ((size_t)(id - 20480) * 256 + threadIdx.x) * 4;
    size_t bh = idx >> 17, rem = idx & 131071;
    float4 a = *(const float4*)(ck + idx);
    u16x4 v;
    v[0] = f2b(a.x); v[1] = f2b(a.y); v[2] = f2b(a.z); v[3] = f2b(a.w);
    *(u16x4*)(Kf + bh * 262144 + rem) = v;
  } else {                                           // build_trig
    int idx = (id - 28672) * 256 + threadIdx.x;
    int s = idx >> 6, i = idx & 63;
    float inv = exp2f(-(float)i * (13.287712379549449f / 64.0f));
    float ang = (float)(1024 + s) * inv;
    cs[idx] = cosf(ang);
    sn[idx] = sinf(ang);
  }
}

// ---------------- post_fused: rope_qk + build_vt (both read qkv) -----------
// blocks [0,4096):       rope_qk (row = id)
// blocks [4096,20480):   build_vt (idx -> bhid, d0, s0)
__global__ __launch_bounds__(256) void post_fused(
    const unsigned short* __restrict__ qkv, const float* __restrict__ cs,
    const float* __restrict__ sn, const float* __restrict__ cv,
    unsigned short* __restrict__ Qb, unsigned short* __restrict__ Kf,
    unsigned short* __restrict__ Vt) {
  __shared__ float tile[32][33];
  int id = blockIdx.x;
  if (id < 4096) {                                   // rope_qk
    int row = id;
    int b = row >> 10, s = row & 1023;
#pragma unroll
    for (int it = 0; it < 4; ++it) {
      int item = it * 256 + threadIdx.x;
      int h = item >> 6, i = item & 63;
      const unsigned short* base = qkv + (size_t)row * 6144 + h * 384;
      float q1 = b2f(base[i]),       q2 = b2f(base[64 + i]);
      float k1 = b2f(base[128 + i]), k2 = b2f(base[192 + i]);
      float c = cs[s * 64 + i], sv = sn[s * 64 + i];
      const float scale = 0.12751738f;  // log2(e)/sqrt(128): base-2 softmax
      size_t bh = (size_t)(b * 16 + h);
      unsigned short* qd = Qb + (bh * 1024 + s) * 128;
      qd[i]      = f2b((q1 * c - q2 * sv) * scale);
      qd[64 + i] = f2b((q2 * c + q1 * sv) * scale);
      unsigned short* kd = Kf + (bh * 2048 + 1024 + s) * 128;
      kd[i]      = f2b(k1 * c - k2 * sv);
      kd[64 + i] = f2b(k2 * c + k1 * sv);
    }
  } else {                                           // build_vt
    int idx = id - 4096;
    int bhid = idx >> 8;
    int rem = idx & 255;
    int d0 = (rem >> 6) * 32, s0 = (rem & 63) * 32;
    int tx = threadIdx.x & 31, ty = threadIdx.x >> 5;
    int b = bhid >> 4, h = bhid & 15;
#pragma unroll
    for (int j = 0; j < 4; ++j) {
      int s = s0 + ty + j * 8, d = d0 + tx;
      float v;
      if (s < 1024) v = cv[((size_t)bhid * 1024 + s) * 128 + d];
      else v = b2f(qkv[((size_t)b * 1024 + (s - 1024)) * 6144 + h * 384 + 256 + d]);
      tile[ty + j * 8][tx] = v;
    }
    __syncthreads();
#pragma unroll
    for (int j = 0; j < 4; ++j) {
      int d = d0 + ty + j * 8, s = s0 + tx;
      Vt[((size_t)bhid * 128 + d) * 2048 + s] = f2b(tile[tx][ty + j * 8]);
    }
  }
}

// ---------------- GEMM: C[M][N] = A[M][K] * B^T  (B given as [N][K]) -------
// r8-exact. Ring-3 counted-vmcnt, BM=256 BN=128 BK=32, 8 waves (4M x 2N),
// per-wave 64x64, 72KB LDS -> 2 blocks/CU. launch_bounds(512,4): the 128-reg
// budget fits acc(64)+frags+addr with NO spill (r11's (512,6) forced 85-reg
// cap -> accumulator spill -> 5GB scratch traffic -> 10x regression).
// 2-bit XOR swizzle: LDS[r][c16] = src[r][c16 ^ ((r>>1)&3)]; frag rows step
// 16 -> per-lane const (l15>>1)&3; measured 0 conflicts (r8).
// Ledger: stage=3 loads; at iter t outstanding {t+1,t+2}=6; vmcnt(3) ->
// tile t+1 arrived; loop-top barrier certifies tile t block-wide; slot
// (t+2)%3 reads retired before that barrier.
template <int M, int N, int K, bool OUT_BF16>
__global__ __launch_bounds__(512, 4) void gemm_ring(
    const unsigned short* __restrict__ A, const unsigned short* __restrict__ B,
    void* __restrict__ Cout) {
  __shared__ __align__(16) char lds[3 * 24576];
  constexpr int NT = N / 128;
  constexpr int Kt = K / 32;
  int bid = blockIdx.x;
  int tm = bid / NT, tn = bid % NT;
  int tid = threadIdx.x;
  int lane = tid & 63, wave = tid >> 6;
  int wr = (wave >> 1) * 64, wc = (wave & 1) * 64;
  int l15 = lane & 15, g = lane >> 4;
  int rcol = (g * 16) ^ (((l15 >> 1) & 3) << 4);   // swizzled chunk in 64B row

  int p = tid * 16;   // byte position in a 16KB/8KB staging region
  int srcCol = (p & 63) ^ (((p >> 7) & 3) << 4);   // inverse swizzle on source
  const unsigned short* aSrc0 = A + (size_t)(tm * 256 + (p >> 6)) * K + (srcCol >> 1);
  const unsigned short* aSrc1 = aSrc0 + (size_t)128 * K;   // rows 128..255
  const unsigned short* bSrc  = B + (size_t)(tn * 128 + (p >> 6)) * K + (srcCol >> 1);

  f32x4 acc[4][4] = {};

  auto stage = [&](int s) {
    char* base = (char*)lds + s * 24576;
    gload_lds16(aSrc0, base + p);
    gload_lds16(aSrc1, base + 8192 + p);
    gload_lds16(bSrc,  base + 16384 + p);
    aSrc0 += 32; aSrc1 += 32; bSrc += 32;
  };

  stage(0);
  stage(1);
  asm volatile("s_waitcnt vmcnt(3)" ::: "memory");   // tile 0 complete (mine)

  int slot = 0, sNext = 2;
  for (int t = 0; t < Kt; ++t) {
    barrier_nodrain();                 // certifies tile t staged block-wide
    if (t + 2 < Kt) {
      stage(sNext);
      sNext = (sNext == 2) ? 0 : sNext + 1;
      asm volatile("s_waitcnt vmcnt(3)" ::: "memory");   // tile t+1 complete (mine)
    } else {
      asm volatile("s_waitcnt vmcnt(0)" ::: "memory");   // tail drain
    }
    const char* As_ = (const char*)lds + slot * 24576;
    const char* Bs_ = As_ + 16384;
    bf16x8 af[4], bfr[4];
#pragma unroll
    for (int m = 0; m < 4; ++m)
      af[m] = *(const bf16x8*)(As_ + (wr + m * 16 + l15) * 64 + rcol);
#pragma unroll
    for (int n = 0; n < 4; ++n)
      bfr[n] = *(const bf16x8*)(Bs_ + (wc + n * 16 + l15) * 64 + rcol);
    __builtin_amdgcn_s_setprio(1);
#pragma unroll
    for (int m = 0; m < 4; ++m)
#pragma unroll
      for (int n = 0; n < 4; ++n)
        acc[m][n] = __builtin_amdgcn_mfma_f32_16x16x32_bf16(af[m], bfr[n], acc[m][n], 0, 0, 0);
    __builtin_amdgcn_s_setprio(0);
    slot = (slot == 2) ? 0 : slot + 1;
  }

#pragma unroll
  for (int m = 0; m < 4; ++m) {
    int row0 = tm * 256 + wr + m * 16 + g * 4;
#pragma unroll
    for (int n = 0; n < 4; ++n) {
      int col = tn * 128 + wc + n * 16 + l15;
#pragma unroll
      for (int r = 0; r < 4; ++r) {
        size_t off = (size_t)(row0 + r) * N + col;
        if constexpr (OUT_BF16) ((unsigned short*)Cout)[off] = f2b(acc[m][n][r]);
        else ((float*)Cout)[off] = acc[m][n][r];
      }
    }
  }
}

// ---------------- Flash attention ------------------------------------------
// grid = 512: bh (64) x q-tile (8 of 128 rows). 4 waves x 32 q rows each
// (2 q-sets of 16 per wave -> each K/V A-frag LDS read feeds 2 MFMAs).
// Double-buffered K/V, counted vmcnt(8).
__global__ __launch_bounds__(256, 2) void attn_kernel(
    const unsigned short* __restrict__ Qb,   // [64][1024][128], pre-scaled
    const unsigned short* __restrict__ Kf,   // [64][2048][128]
    const unsigned short* __restrict__ Vt,   // [64][128][2048]
    unsigned short* __restrict__ Out) {      // [4096][2048] = [b][s][h*128+d]
  __shared__ __align__(16) unsigned short Ks[2][64 * 128];  // 2x16KB, swizzled
  __shared__ __align__(16) unsigned short Vs[2][64 * 128];  // 2x16KB, swizzled
  __shared__ __align__(16) char PsRaw[4 * 2 * 2048];        // 16KB: wave, qset
  // total LDS = 81920 -> exactly 2 blocks/CU

  int raw = blockIdx.x;
  int sb = (raw & 7) * 64 + (raw >> 3);     // XCD swizzle: 8 heads per XCD
  int bh = sb >> 3, qt = sb & 7;
  int tid = threadIdx.x, lane = tid & 63, wave = tid >> 6;
  int l15 = lane & 15, g = lane >> 4;
  int swz = (l15 & 7) << 4;

  int qrow0 = qt * 128 + wave * 32;
  bf16x8 qf0[4], qf1[4];
  const unsigned short* qp0 = Qb + ((size_t)(bh * 1024 + qrow0 + l15)) * 128;
#pragma unroll
  for (int kk = 0; kk < 4; ++kk) {
    qf0[kk] = *(const bf16x8*)(qp0 + kk * 32 + g * 8);
    qf1[kk] = *(const bf16x8*)(qp0 + 16 * 128 + kk * 32 + g * 8);
  }

  u16x8 ou;
#pragma unroll
  for (int j = 0; j < 8; ++j) ou[j] = 0x3F80;           // bf16 1.0
  bf16x8 ones = __builtin_bit_cast(bf16x8, ou);

  // hoisted staging pointers (incremented per kv-tile)
  const unsigned short* Kbase = Kf + (size_t)bh * 2048 * 128;
  const unsigned short* Vbase = Vt + (size_t)bh * 128 * 2048;
  const unsigned short* kptr[4];
  const unsigned short* vptr[4];
  char* kdst0[4];
  char* vdst0[4];
#pragma unroll
  for (int is = 0; is < 4; ++is) {
    int p = tid * 16 + is * 4096;
    int lgk = p ^ (((p >> 8) & 7) << 4);          // K rows = 256B
    kptr[is] = Kbase + (size_t)(lgk >> 8) * 128 + ((lgk & 255) >> 1);
    kdst0[is] = (char*)Ks + is * 4096 + (tid & 192) * 16;
    int lgv = p ^ (((p >> 7) & 7) << 4);          // V^T rows = 128B
    vptr[is] = Vbase + (size_t)(lgv >> 7) * 2048 + ((lgv & 127) >> 1);
    vdst0[is] = (char*)Vs + is * 4096 + (tid & 192) * 16;
  }
  char* ps0 = PsRaw + wave * 4096 + l15 * 128;
  char* ps1 = ps0 + 2048;

  auto stage = [&](int buf) {
#pragma unroll
    for (int is = 0; is < 4; ++is) {
      gload_lds16(kptr[is], kdst0[is] + buf * 16384);  kptr[is] += 64 * 128;
      gload_lds16(vptr[is], vdst0[is] + buf * 16384);  vptr[is] += 64;
    }
  };

  float mrun0 = -1e30f, mrun1 = -1e30f;
  f32x4 acc0[8] = {}, acc1[8] = {};
  f32x4 accl0 = {}, accl1 = {};

  // softmax+pack for one q-set (all loops unrolled -> static indexing)
  auto softmax_pack = [&](f32x4* st, float& mrun, f32x4* accp, f32x4& accl,
                          char* ps) {
    float m0 = fmaxf(fmaxf(st[0][0], st[0][1]), st[0][2]);
    float m1 = fmaxf(fmaxf(st[0][3], st[1][0]), st[1][1]);
    float m2 = fmaxf(fmaxf(st[1][2], st[1][3]), st[2][0]);
    float m3 = fmaxf(fmaxf(st[2][1], st[2][2]), st[2][3]);
    float m4 = fmaxf(fmaxf(st[3][0], st[3][1]), st[3][2]);
    float pmax = fmaxf(fmaxf(fmaxf(m0, m1), fmaxf(m2, m3)), fmaxf(m4, st[3][3]));
    pmax = fmaxf(pmax, __shfl_xor(pmax, 16));
    pmax = fmaxf(pmax, __shfl_xor(pmax, 32));
    if (!__all(pmax - mrun <= 8.0f)) {          // defer-max (T13)
      float mnew = fmaxf(mrun, pmax);
      float corr = exp2f(mrun - mnew);
      accl *= corr;
#pragma unroll
      for (int mt = 0; mt < 8; ++mt) accp[mt] *= corr;
      mrun = mnew;
    }
#pragma unroll
    for (int t = 0; t < 4; ++t) {
      float p0 = exp2f(st[t][0] - mrun);
      float p1 = exp2f(st[t][1] - mrun);
      float p2 = exp2f(st[t][2] - mrun);
      float p3 = exp2f(st[t][3] - mrun);
      uint2 w;
      w.x = cvt_pk_bf16(p0, p1);
      w.y = cvt_pk_bf16(p2, p3);
      *(uint2*)(ps + ((t * 32 + g * 8) ^ swz)) = w;
    }
  };

  stage(0);
  for (int it = 0; it < 32; ++it) {
    int cur = it & 1;
    barrier_nodrain();          // prev compute done -> buf cur^1 reads retired
    if (it + 1 < 32) {
      stage(cur ^ 1);
      asm volatile("s_waitcnt vmcnt(8)" ::: "memory");  // tile it arrived (mine)
    } else {
      asm volatile("s_waitcnt vmcnt(0)" ::: "memory");  // tail drain
    }
    barrier_nodrain();          // tile it visible block-wide
    const char* ksA = (const char*)Ks + cur * 16384 + l15 * 256;
    const char* vsA = (const char*)Vs + cur * 16384 + l15 * 128;

    // S^T tiles: 4 x (16 kv x 16 q) x 2 q-sets; one A-read feeds 2 MFMAs
    f32x4 st0[4] = {}, st1[4] = {};
#pragma unroll
    for (int kk = 0; kk < 4; ++kk) {
#pragma unroll
      for (int t = 0; t < 4; ++t) {
        bf16x8 a = *(const bf16x8*)(ksA + t * 4096 + ((kk * 64 + g * 16) ^ swz));
        st0[t] = __builtin_amdgcn_mfma_f32_16x16x32_bf16(a, qf0[kk], st0[t], 0, 0, 0);
        st1[t] = __builtin_amdgcn_mfma_f32_16x16x32_bf16(a, qf1[kk], st1[t], 0, 0, 0);
      }
    }

    softmax_pack(st0, mrun0, acc0, accl0, ps0);
    softmax_pack(st1, mrun1, acc1, accl1, ps1);

    // out^T += V^T * P^T (both q-sets per V A-read); lsum via ones-MFMA
#pragma unroll
    for (int k2 = 0; k2 < 2; ++k2) {
      bf16x8 p0 = *(const bf16x8*)(ps0 + ((k2 * 64 + g * 16) ^ swz));
      bf16x8 p1 = *(const bf16x8*)(ps1 + ((k2 * 64 + g * 16) ^ swz));
      accl0 = __builtin_amdgcn_mfma_f32_16x16x32_bf16(ones, p0, accl0, 0, 0, 0);
      accl1 = __builtin_amdgcn_mfma_f32_16x16x32_bf16(ones, p1, accl1, 0, 0, 0);
#pragma unroll
      for (int mt = 0; mt < 8; ++mt) {
        bf16x8 a = *(const bf16x8*)(vsA + mt * 2048 + ((k2 * 64 + g * 16) ^ swz));
        acc0[mt] = __builtin_amdgcn_mfma_f32_16x16x32_bf16(a, p0, acc0[mt], 0, 0, 0);
        acc1[mt] = __builtin_amdgcn_mfma_f32_16x16x32_bf16(a, p1, acc1[mt], 0, 0, 0);
      }
    }
  }

  float inv0 = 1.f / accl0[0];
  float inv1 = 1.f / accl1[0];
  int b = bh >> 4, h = bh & 15;
  int sq = qt * 128 + wave * 32 + l15;
  unsigned short* orow0 = Out + ((size_t)(b * 1024 + sq) * 16 + h) * 128;
  unsigned short* orow1 = orow0 + (size_t)16 * 2048;
#pragma unroll
  for (int mt = 0; mt < 8; ++mt) {
    uint2 w0, w1;
    w0.x = cvt_pk_bf16(acc0[mt][0] * inv0, acc0[mt][1] * inv0);
    w0.y = cvt_pk_bf16(acc0[mt][2] * inv0, acc0[mt][3] * inv0);
    w1.x = cvt_pk_bf16(acc1[mt][0] * inv1, acc1[mt][1] * inv1);
    w1.y = cvt_pk_bf16(acc1[mt][2] * inv1, acc1[mt][3] * inv1);
    *(uint2*)(orow0 + mt * 16 + g * 4) = w0;
    *(uint2*)(orow1 + mt * 16 + g * 4) = w1;
  }
}

// ---------------------------------------------------------------------------
extern "C" void kernel_launch(void* const* d_in, const int* in_sizes, int n_in,
                              void* d_out, int out_size, void* d_ws, size_t ws_size,
                              hipStream_t stream) {
  const float* x       = (const float*)d_in[0];
  const float* cache_k = (const float*)d_in[1];
  const float* cache_v = (const float*)d_in[2];
  const float* w_qkv   = (const float*)d_in[3];
  const float* w_o     = (const float*)d_in[4];
  float* out = (float*)d_out;

  // workspace layout (~176.5 MiB)
  char* W = (char*)d_ws;
  constexpr size_t O_TRIG = 0;                       // 2 * 256KB
  constexpr size_t O_XB   = 524288;                  // 16MB (reused as attn_out)
  constexpr size_t O_WQT  = O_XB  + 16777216;        // 24MB
  constexpr size_t O_WOT  = O_WQT + 25165824;        // 8MB
  constexpr size_t O_QKV  = O_WOT + 8388608;         // 48MB
  constexpr size_t O_QB   = O_QKV + 50331648;        // 16MB
  constexpr size_t O_KF   = O_QB  + 16777216;        // 32MB
  constexpr size_t O_VT   = O_KF  + 33554432;        // 32MB
  float* cs_tab = (float*)(W + O_TRIG);
  float* sn_tab = (float*)(W + O_TRIG + 262144);
  unsigned short* xb   = (unsigned short*)(W + O_XB);
  unsigned short* wqT  = (unsigned short*)(W + O_WQT);
  unsigned short* woT  = (unsigned short*)(W + O_WOT);
  unsigned short* qkv  = (unsigned short*)(W + O_QKV);
  unsigned short* qb   = (unsigned short*)(W + O_QB);
  unsigned short* Kf   = (unsigned short*)(W + O_KF);
  unsigned short* Vt   = (unsigned short*)(W + O_VT);
  unsigned short* attn_out = xb;   // xb dead after gemm1

  prep_fused<<<28928, 256, 0, stream>>>(x, cache_k, w_qkv, w_o,
                                        xb, Kf, wqT, woT, cs_tab, sn_tab);
  gemm_ring<4096, 6144, 2048, true><<<768, 512, 0, stream>>>(xb, wqT, qkv);
  post_fused<<<20480, 256, 0, stream>>>(qkv, cs_tab, sn_tab, cache_v,
                                        qb, Kf, Vt);
  attn_kernel<<<512, 256, 0, stream>>>(qb, Kf, Vt, attn_out);
  gemm_ring<4096, 2048, 2048, false><<<256, 512, 0, stream>>>(attn_out, woT, out);
}

// Round 13
// 296.111 us; speedup vs baseline: 5.2890x; 1.0773x over previous
//
#include <hip/hip_runtime.h>

// ---------------------------------------------------------------------------
// Attention layer: qkv proj -> RoPE -> concat KV cache -> softmax attn -> out proj
// B=4 Sq=1024 Skv_cache=1024 H=16 D=128 D_MODEL=2048
// 4 launches: prep_fused -> gemm1 (rope+qkv-scatter epilogue) -> attn -> gemm2.
// GEMM core: r8-exact ring-3 counted-vmcnt (BM256 BN128 BK32, (512,4),
// 2-bit XOR swizzle, 0 conflicts). Wave cols remapped to (wave&1)*16+n*32+l15
// so RoPE pairs (i,i+64) = acc[m][n] / acc[m][n+2] are thread-local.
// Flash attention: r5 structure (32 q/wave, dbuf K/V), grid 512.
// ---------------------------------------------------------------------------

typedef __bf16 bf16x8 __attribute__((ext_vector_type(8)));
typedef float f32x4 __attribute__((ext_vector_type(4)));
typedef unsigned short u16x8 __attribute__((ext_vector_type(8)));
typedef unsigned short u16x4 __attribute__((ext_vector_type(4)));

__device__ __forceinline__ float b2f(unsigned short u) {
  return __builtin_bit_cast(float, (unsigned int)u << 16);
}
__device__ __forceinline__ unsigned short f2b(float f) {
  unsigned int x = __builtin_bit_cast(unsigned int, f);
  x += 0x7fffu + ((x >> 16) & 1u);   // RNE (finite values only)
  return (unsigned short)(x >> 16);
}
__device__ __forceinline__ unsigned int cvt_pk_bf16(float lo, float hi) {
  unsigned int r;
  asm("v_cvt_pk_bf16_f32 %0, %1, %2" : "=v"(r) : "v"(lo), "v"(hi));
  return r;
}
__device__ __forceinline__ void gload_lds16(const void* g, void* l) {
  __builtin_amdgcn_global_load_lds(
      (__attribute__((address_space(1))) void*)(g),
      (__attribute__((address_space(3))) void*)(l), 16, 0, 0);
}
__device__ __forceinline__ void barrier_nodrain() {
  asm volatile("" ::: "memory");
  __builtin_amdgcn_s_barrier();
  asm volatile("" ::: "memory");
}

// ---------------- prep_fused: ALL input-only data movement in ONE launch ---
// [0,4096):        conv_bf16 of x
// [4096,16384):    transpose w_qkv [2048][6144] -> wqT [6144][2048]
// [16384,20480):   transpose w_o   [2048][2048] -> woT
// [20480,28672):   copy_k cache_k -> Kf[:, :1024] bf16
// [28672,28928):   build_trig
// [28928,37120):   transpose cache_v -> Vt[:, :1024]  (s<1024 half)
__global__ __launch_bounds__(256) void prep_fused(
    const float* __restrict__ x, const float* __restrict__ ck,
    const float* __restrict__ cv, const float* __restrict__ wqkv,
    const float* __restrict__ wo, unsigned short* __restrict__ xb,
    unsigned short* __restrict__ Kf, unsigned short* __restrict__ Vt,
    unsigned short* __restrict__ wqT, unsigned short* __restrict__ woT,
    float* __restrict__ cs, float* __restrict__ sn) {
  __shared__ float tile[32][33];
  int id = blockIdx.x;
  if (id < 4096) {                                   // conv_bf16
    size_t i = ((size_t)id * 256 + threadIdx.x) * 8;
    float4 a = *(const float4*)(x + i);
    float4 b = *(const float4*)(x + i + 4);
    u16x8 v;
    v[0] = f2b(a.x); v[1] = f2b(a.y); v[2] = f2b(a.z); v[3] = f2b(a.w);
    v[4] = f2b(b.x); v[5] = f2b(b.y); v[6] = f2b(b.z); v[7] = f2b(b.w);
    *(u16x8*)(xb + i) = v;
  } else if (id < 20480) {                           // weight transposes
    const float* in;  unsigned short* out;  int R, C, idx;
    if (id < 16384) { in = wqkv; out = wqT; R = 2048; C = 6144; idx = id - 4096; }
    else            { in = wo;   out = woT; R = 2048; C = 2048; idx = id - 16384; }
    int nc = C >> 5;
    int c0 = (idx % nc) * 32, r0 = (idx / nc) * 32;
    int tx = threadIdx.x & 31, ty = threadIdx.x >> 5;
#pragma unroll
    for (int j = 0; j < 4; ++j)
      tile[ty + j * 8][tx] = in[(size_t)(r0 + ty + j * 8) * C + c0 + tx];
    __syncthreads();
#pragma unroll
    for (int j = 0; j < 4; ++j)
      out[(size_t)(c0 + ty + j * 8) * R + r0 + tx] = f2b(tile[tx][ty + j * 8]);
  } else if (id < 28672) {                           // copy_k
    size_t idx = ((size_t)(id - 20480) * 256 + threadIdx.x) * 4;
    size_t bh = idx >> 17, rem = idx & 131071;
    float4 a = *(const float4*)(ck + idx);
    u16x4 v;
    v[0] = f2b(a.x); v[1] = f2b(a.y); v[2] = f2b(a.z); v[3] = f2b(a.w);
    *(u16x4*)(Kf + bh * 262144 + rem) = v;
  } else if (id < 28928) {                           // build_trig
    int idx = (id - 28672) * 256 + threadIdx.x;
    int s = idx >> 6, i = idx & 63;
    float inv = exp2f(-(float)i * (13.287712379549449f / 64.0f));
    float ang = (float)(1024 + s) * inv;
    cs[idx] = cosf(ang);
    sn[idx] = sinf(ang);
  } else {                                           // cache_v transpose
    int idx = id - 28928;                            // 8192: bhid x 128 tiles
    int bhid = idx >> 7;
    int rem = idx & 127;
    int d0 = (rem >> 5) * 32, s0 = (rem & 31) * 32;
    int tx = threadIdx.x & 31, ty = threadIdx.x >> 5;
#pragma unroll
    for (int j = 0; j < 4; ++j)
      tile[ty + j * 8][tx] = cv[((size_t)bhid * 1024 + s0 + ty + j * 8) * 128 + d0 + tx];
    __syncthreads();
#pragma unroll
    for (int j = 0; j < 4; ++j)
      Vt[((size_t)bhid * 128 + d0 + ty + j * 8) * 2048 + s0 + tx] =
          f2b(tile[tx][ty + j * 8]);
  }
}

// ---------------- GEMM: C[M][N] = A[M][K] * B^T  (B given as [N][K]) -------
// Core: r8-exact ring-3 counted-vmcnt, BM=256 BN=128 BK=32, 8 waves (4M x
// "2N"), 72KB LDS -> 2 blocks/CU, launch_bounds(512,4) (128-reg budget; the
// (512,6) variant spilled acc -> 10x regression, r11). 2-bit XOR swizzle
// (0 conflicts measured). Wave col map: col = (wave&1)*16 + n*32 + l15 ->
// each wave owns cols {wc1*16 + 0-15,32-47,64-79,96-111}; rope pair (i,i+64)
// = (acc[m][n], acc[m][n+2]) same thread/row.
// MODE 0: C = f32 row-major (gemm2).
// MODE 1: qkv-fused epilogue (gemm1): tile tn is q/k/v of head tn/3
//   (384 = 3x128 aligned). q: rope+scale -> Qb; k: rope -> Kf[:,1024:];
//   v: transposed scatter -> Vt[:,1024:].
// Ledger (race-free since r5): stage=3 loads; outstanding {t+1,t+2}=6;
// vmcnt(3) -> tile t+1 arrived; loop-top barrier certifies tile t.
template <int M, int N, int K, int MODE>
__global__ __launch_bounds__(512, 4) void gemm_ring(
    const unsigned short* __restrict__ A, const unsigned short* __restrict__ B,
    void* __restrict__ Cout, const float* __restrict__ cs,
    const float* __restrict__ sn, unsigned short* __restrict__ Qb,
    unsigned short* __restrict__ Kf, unsigned short* __restrict__ Vt) {
  __shared__ __align__(16) char lds[3 * 24576];
  constexpr int NT = N / 128;
  constexpr int Kt = K / 32;
  int bid = blockIdx.x;
  int tm = bid / NT, tn = bid % NT;
  int tid = threadIdx.x;
  int lane = tid & 63, wave = tid >> 6;
  int wr = (wave >> 1) * 64;
  int wc1 = wave & 1;
  int l15 = lane & 15, g = lane >> 4;
  int rcol = (g * 16) ^ (((l15 >> 1) & 3) << 4);   // swizzled chunk in 64B row

  int p = tid * 16;
  int srcCol = (p & 63) ^ (((p >> 7) & 3) << 4);   // inverse swizzle on source
  const unsigned short* aSrc0 = A + (size_t)(tm * 256 + (p >> 6)) * K + (srcCol >> 1);
  const unsigned short* aSrc1 = aSrc0 + (size_t)128 * K;
  const unsigned short* bSrc  = B + (size_t)(tn * 128 + (p >> 6)) * K + (srcCol >> 1);

  f32x4 acc[4][4] = {};

  auto stage = [&](int s) {
    char* base = (char*)lds + s * 24576;
    gload_lds16(aSrc0, base + p);
    gload_lds16(aSrc1, base + 8192 + p);
    gload_lds16(bSrc,  base + 16384 + p);
    aSrc0 += 32; aSrc1 += 32; bSrc += 32;
  };

  stage(0);
  stage(1);
  asm volatile("s_waitcnt vmcnt(3)" ::: "memory");   // tile 0 complete (mine)

  int slot = 0, sNext = 2;
  for (int t = 0; t < Kt; ++t) {
    barrier_nodrain();                 // certifies tile t staged block-wide
    if (t + 2 < Kt) {
      stage(sNext);
      sNext = (sNext == 2) ? 0 : sNext + 1;
      asm volatile("s_waitcnt vmcnt(3)" ::: "memory");   // tile t+1 complete
    } else {
      asm volatile("s_waitcnt vmcnt(0)" ::: "memory");   // tail drain
    }
    const char* As_ = (const char*)lds + slot * 24576;
    const char* Bs_ = As_ + 16384;
    bf16x8 af[4], bfr[4];
#pragma unroll
    for (int m = 0; m < 4; ++m)
      af[m] = *(const bf16x8*)(As_ + (wr + m * 16 + l15) * 64 + rcol);
#pragma unroll
    for (int n = 0; n < 4; ++n)
      bfr[n] = *(const bf16x8*)(Bs_ + (wc1 * 16 + n * 32 + l15) * 64 + rcol);
    __builtin_amdgcn_s_setprio(1);
#pragma unroll
    for (int m = 0; m < 4; ++m)
#pragma unroll
      for (int n = 0; n < 4; ++n)
        acc[m][n] = __builtin_amdgcn_mfma_f32_16x16x32_bf16(af[m], bfr[n], acc[m][n], 0, 0, 0);
    __builtin_amdgcn_s_setprio(0);
    slot = (slot == 2) ? 0 : slot + 1;
  }

  if constexpr (MODE == 0) {
#pragma unroll
    for (int m = 0; m < 4; ++m) {
      int row0 = tm * 256 + wr + m * 16 + g * 4;
#pragma unroll
      for (int n = 0; n < 4; ++n) {
        int col = tn * 128 + wc1 * 16 + n * 32 + l15;
#pragma unroll
        for (int r = 0; r < 4; ++r)
          ((float*)Cout)[(size_t)(row0 + r) * N + col] = acc[m][n][r];
      }
    }
  } else {
    int part = tn % 3, h = tn / 3;         // tile is q/k/v of head h
    size_t bh = (size_t)(tm >> 2) * 16 + h;
    if (part == 2) {                       // v -> Vt[bh][d][1024+s]
#pragma unroll
      for (int m = 0; m < 4; ++m) {
        int s0 = (tm & 3) * 256 + wr + m * 16 + g * 4;
#pragma unroll
        for (int n = 0; n < 4; ++n) {
          int d = wc1 * 16 + n * 32 + l15;
          uint2 w;
          w.x = cvt_pk_bf16(acc[m][n][0], acc[m][n][1]);
          w.y = cvt_pk_bf16(acc[m][n][2], acc[m][n][3]);
          *(uint2*)(Vt + (bh * 128 + d) * 2048 + 1024 + s0) = w;
        }
      }
    } else {                               // q/k: rope in-register
      const float qscale = 0.12751738f;    // log2(e)/sqrt(128)
#pragma unroll
      for (int m = 0; m < 4; ++m) {
        int s0 = (tm & 3) * 256 + wr + m * 16 + g * 4;
#pragma unroll
        for (int n = 0; n < 2; ++n) {
          int i1 = wc1 * 16 + n * 32 + l15;
#pragma unroll
          for (int r = 0; r < 4; ++r) {
            int s = s0 + r;
            float c = cs[s * 64 + i1], sv = sn[s * 64 + i1];
            float v1 = acc[m][n][r], v2 = acc[m][n + 2][r];
            float o1 = v1 * c - v2 * sv;
            float o2 = v2 * c + v1 * sv;
            unsigned short* dst;
            if (part == 0) {
              o1 *= qscale; o2 *= qscale;
              dst = Qb + (bh * 1024 + s) * 128;
            } else {
              dst = Kf + (bh * 2048 + 1024 + s) * 128;
            }
            dst[i1] = f2b(o1);
            dst[i1 + 64] = f2b(o2);
          }
        }
      }
    }
  }
}

// ---------------- Flash attention ------------------------------------------
// grid = 512: bh (64) x q-tile (8 of 128 rows). 4 waves x 32 q rows each
// (2 q-sets of 16 per wave). Double-buffered K/V, counted vmcnt(8).
__global__ __launch_bounds__(256, 2) void attn_kernel(
    const unsigned short* __restrict__ Qb,   // [64][1024][128], pre-scaled
    const unsigned short* __restrict__ Kf,   // [64][2048][128]
    const unsigned short* __restrict__ Vt,   // [64][128][2048]
    unsigned short* __restrict__ Out) {      // [4096][2048] = [b][s][h*128+d]
  __shared__ __align__(16) unsigned short Ks[2][64 * 128];  // 2x16KB, swizzled
  __shared__ __align__(16) unsigned short Vs[2][64 * 128];  // 2x16KB, swizzled
  __shared__ __align__(16) char PsRaw[4 * 2 * 2048];        // 16KB: wave, qset
  // total LDS = 81920 -> exactly 2 blocks/CU

  int raw = blockIdx.x;
  int sb = (raw & 7) * 64 + (raw >> 3);     // XCD swizzle: 8 heads per XCD
  int bh = sb >> 3, qt = sb & 7;
  int tid = threadIdx.x, lane = tid & 63, wave = tid >> 6;
  int l15 = lane & 15, g = lane >> 4;
  int swz = (l15 & 7) << 4;

  int qrow0 = qt * 128 + wave * 32;
  bf16x8 qf0[4], qf1[4];
  const unsigned short* qp0 = Qb + ((size_t)(bh * 1024 + qrow0 + l15)) * 128;
#pragma unroll
  for (int kk = 0; kk < 4; ++kk) {
    qf0[kk] = *(const bf16x8*)(qp0 + kk * 32 + g * 8);
    qf1[kk] = *(const bf16x8*)(qp0 + 16 * 128 + kk * 32 + g * 8);
  }

  u16x8 ou;
#pragma unroll
  for (int j = 0; j < 8; ++j) ou[j] = 0x3F80;           // bf16 1.0
  bf16x8 ones = __builtin_bit_cast(bf16x8, ou);

  // hoisted staging pointers (incremented per kv-tile)
  const unsigned short* Kbase = Kf + (size_t)bh * 2048 * 128;
  const unsigned short* Vbase = Vt + (size_t)bh * 128 * 2048;
  const unsigned short* kptr[4];
  const unsigned short* vptr[4];
  char* kdst0[4];
  char* vdst0[4];
#pragma unroll
  for (int is = 0; is < 4; ++is) {
    int p = tid * 16 + is * 4096;
    int lgk = p ^ (((p >> 8) & 7) << 4);          // K rows = 256B
    kptr[is] = Kbase + (size_t)(lgk >> 8) * 128 + ((lgk & 255) >> 1);
    kdst0[is] = (char*)Ks + is * 4096 + (tid & 192) * 16;
    int lgv = p ^ (((p >> 7) & 7) << 4);          // V^T rows = 128B
    vptr[is] = Vbase + (size_t)(lgv >> 7) * 2048 + ((lgv & 127) >> 1);
    vdst0[is] = (char*)Vs + is * 4096 + (tid & 192) * 16;
  }
  char* ps0 = PsRaw + wave * 4096 + l15 * 128;
  char* ps1 = ps0 + 2048;

  auto stage = [&](int buf) {
#pragma unroll
    for (int is = 0; is < 4; ++is) {
      gload_lds16(kptr[is], kdst0[is] + buf * 16384);  kptr[is] += 64 * 128;
      gload_lds16(vptr[is], vdst0[is] + buf * 16384);  vptr[is] += 64;
    }
  };

  float mrun0 = -1e30f, mrun1 = -1e30f;
  f32x4 acc0[8] = {}, acc1[8] = {};
  f32x4 accl0 = {}, accl1 = {};

  auto softmax_pack = [&](f32x4* st, float& mrun, f32x4* accp, f32x4& accl,
                          char* ps) {
    float m0 = fmaxf(fmaxf(st[0][0], st[0][1]), st[0][2]);
    float m1 = fmaxf(fmaxf(st[0][3], st[1][0]), st[1][1]);
    float m2 = fmaxf(fmaxf(st[1][2], st[1][3]), st[2][0]);
    float m3 = fmaxf(fmaxf(st[2][1], st[2][2]), st[2][3]);
    float m4 = fmaxf(fmaxf(st[3][0], st[3][1]), st[3][2]);
    float pmax = fmaxf(fmaxf(fmaxf(m0, m1), fmaxf(m2, m3)), fmaxf(m4, st[3][3]));
    pmax = fmaxf(pmax, __shfl_xor(pmax, 16));
    pmax = fmaxf(pmax, __shfl_xor(pmax, 32));
    if (!__all(pmax - mrun <= 8.0f)) {          // defer-max (T13)
      float mnew = fmaxf(mrun, pmax);
      float corr = exp2f(mrun - mnew);
      accl *= corr;
#pragma unroll
      for (int mt = 0; mt < 8; ++mt) accp[mt] *= corr;
      mrun = mnew;
    }
#pragma unroll
    for (int t = 0; t < 4; ++t) {
      float p0 = exp2f(st[t][0] - mrun);
      float p1 = exp2f(st[t][1] - mrun);
      float p2 = exp2f(st[t][2] - mrun);
      float p3 = exp2f(st[t][3] - mrun);
      uint2 w;
      w.x = cvt_pk_bf16(p0, p1);
      w.y = cvt_pk_bf16(p2, p3);
      *(uint2*)(ps + ((t * 32 + g * 8) ^ swz)) = w;
    }
  };

  stage(0);
  for (int it = 0; it < 32; ++it) {
    int cur = it & 1;
    barrier_nodrain();          // prev compute done -> buf cur^1 reads retired
    if (it + 1 < 32) {
      stage(cur ^ 1);
      asm volatile("s_waitcnt vmcnt(8)" ::: "memory");  // tile it arrived
    } else {
      asm volatile("s_waitcnt vmcnt(0)" ::: "memory");  // tail drain
    }
    barrier_nodrain();          // tile it visible block-wide
    const char* ksA = (const char*)Ks + cur * 16384 + l15 * 256;
    const char* vsA = (const char*)Vs + cur * 16384 + l15 * 128;

    f32x4 st0[4] = {}, st1[4] = {};
#pragma unroll
    for (int kk = 0; kk < 4; ++kk) {
#pragma unroll
      for (int t = 0; t < 4; ++t) {
        bf16x8 a = *(const bf16x8*)(ksA + t * 4096 + ((kk * 64 + g * 16) ^ swz));
        st0[t] = __builtin_amdgcn_mfma_f32_16x16x32_bf16(a, qf0[kk], st0[t], 0, 0, 0);
        st1[t] = __builtin_amdgcn_mfma_f32_16x16x32_bf16(a, qf1[kk], st1[t], 0, 0, 0);
      }
    }

    softmax_pack(st0, mrun0, acc0, accl0, ps0);
    softmax_pack(st1, mrun1, acc1, accl1, ps1);

#pragma unroll
    for (int k2 = 0; k2 < 2; ++k2) {
      bf16x8 p0 = *(const bf16x8*)(ps0 + ((k2 * 64 + g * 16) ^ swz));
      bf16x8 p1 = *(const bf16x8*)(ps1 + ((k2 * 64 + g * 16) ^ swz));
      accl0 = __builtin_amdgcn_mfma_f32_16x16x32_bf16(ones, p0, accl0, 0, 0, 0);
      accl1 = __builtin_amdgcn_mfma_f32_16x16x32_bf16(ones, p1, accl1, 0, 0, 0);
#pragma unroll
      for (int mt = 0; mt < 8; ++mt) {
        bf16x8 a = *(const bf16x8*)(vsA + mt * 2048 + ((k2 * 64 + g * 16) ^ swz));
        acc0[mt] = __builtin_amdgcn_mfma_f32_16x16x32_bf16(a, p0, acc0[mt], 0, 0, 0);
        acc1[mt] = __builtin_amdgcn_mfma_f32_16x16x32_bf16(a, p1, acc1[mt], 0, 0, 0);
      }
    }
  }

  float inv0 = 1.f / accl0[0];
  float inv1 = 1.f / accl1[0];
  int b = bh >> 4, h = bh & 15;
  int sq = qt * 128 + wave * 32 + l15;
  unsigned short* orow0 = Out + ((size_t)(b * 1024 + sq) * 16 + h) * 128;
  unsigned short* orow1 = orow0 + (size_t)16 * 2048;
#pragma unroll
  for (int mt = 0; mt < 8; ++mt) {
    uint2 w0, w1;
    w0.x = cvt_pk_bf16(acc0[mt][0] * inv0, acc0[mt][1] * inv0);
    w0.y = cvt_pk_bf16(acc0[mt][2] * inv0, acc0[mt][3] * inv0);
    w1.x = cvt_pk_bf16(acc1[mt][0] * inv1, acc1[mt][1] * inv1);
    w1.y = cvt_pk_bf16(acc1[mt][2] * inv1, acc1[mt][3] * inv1);
    *(uint2*)(orow0 + mt * 16 + g * 4) = w0;
    *(uint2*)(orow1 + mt * 16 + g * 4) = w1;
  }
}

// ---------------------------------------------------------------------------
extern "C" void kernel_launch(void* const* d_in, const int* in_sizes, int n_in,
                              void* d_out, int out_size, void* d_ws, size_t ws_size,
                              hipStream_t stream) {
  const float* x       = (const float*)d_in[0];
  const float* cache_k = (const float*)d_in[1];
  const float* cache_v = (const float*)d_in[2];
  const float* w_qkv   = (const float*)d_in[3];
  const float* w_o     = (const float*)d_in[4];
  float* out = (float*)d_out;

  // workspace layout
  char* W = (char*)d_ws;
  constexpr size_t O_TRIG = 0;                       // 2 * 256KB
  constexpr size_t O_XB   = 524288;                  // 16MB (reused as attn_out)
  constexpr size_t O_WQT  = O_XB  + 16777216;        // 24MB
  constexpr size_t O_WOT  = O_WQT + 25165824;        // 8MB
  constexpr size_t O_QB   = O_WOT + 8388608;         // 16MB
  constexpr size_t O_KF   = O_QB  + 16777216;        // 32MB
  constexpr size_t O_VT   = O_KF  + 33554432;        // 32MB
  float* cs_tab = (float*)(W + O_TRIG);
  float* sn_tab = (float*)(W + O_TRIG + 262144);
  unsigned short* xb   = (unsigned short*)(W + O_XB);
  unsigned short* wqT  = (unsigned short*)(W + O_WQT);
  unsigned short* woT  = (unsigned short*)(W + O_WOT);
  unsigned short* qb   = (unsigned short*)(W + O_QB);
  unsigned short* Kf   = (unsigned short*)(W + O_KF);
  unsigned short* Vt   = (unsigned short*)(W + O_VT);
  unsigned short* attn_out = xb;   // xb dead after gemm1

  prep_fused<<<37120, 256, 0, stream>>>(x, cache_k, cache_v, w_qkv, w_o,
                                        xb, Kf, Vt, wqT, woT, cs_tab, sn_tab);
  gemm_ring<4096, 6144, 2048, 1><<<768, 512, 0, stream>>>(
      xb, wqT, nullptr, cs_tab, sn_tab, qb, Kf, Vt);
  attn_kernel<<<512, 256, 0, stream>>>(qb, Kf, Vt, attn_out);
  gemm_ring<4096, 2048, 2048, 0><<<256, 512, 0, stream>>>(
      attn_out, woT, out, nullptr, nullptr, nullptr, nullptr, nullptr);
}